// Round 1
// baseline (183.041 us; speedup 1.0000x reference)
//
#include <hip/hip_runtime.h>

#define FDIM 256
#define K2   512
#define DNB  32
#define TM   32
#define KB   8

// Precomputed combined weights (recomputed every launch — deterministic).
__device__ float g_WcT[K2 * FDIM];   // [k][o]: k<256 -> W2a^T ; k>=256 -> C1^T
__device__ float g_c2[FDIM];
__device__ float g_c3[FDIM];
__device__ float g_W1s[FDIM];

// ---------- precompute: W1s[j] = sum_k W1[j, 256+k] ----------
__global__ __launch_bounds__(64) void pre_w1s(const float* __restrict__ W1) {
    int j = blockIdx.x;
    int lane = threadIdx.x;
    const float4* row = (const float4*)(W1 + (size_t)j * K2 + FDIM);
    float4 v = row[lane];
    float s = v.x + v.y + v.z + v.w;
    #pragma unroll
    for (int d = 32; d; d >>= 1) s += __shfl_down(s, d);
    if (lane == 0) g_W1s[j] = s;
}

// ---------- precompute: WcT, c2, c3 ----------
__global__ __launch_bounds__(256) void pre_wc(const float* __restrict__ W1,
                                              const float* __restrict__ W2,
                                              const float* __restrict__ b1,
                                              const float* __restrict__ b2,
                                              float Dmul) {
    int o = blockIdx.x;
    int k = threadIdx.x;
    const float* w2b = W2 + (size_t)o * K2 + FDIM;

    // C1[o,k] = sum_j W2b[o,j] * W1[j,k]
    float acc = 0.f;
    #pragma unroll 8
    for (int j = 0; j < FDIM; ++j)
        acc = fmaf(w2b[j], W1[(size_t)j * K2 + k], acc);
    g_WcT[(size_t)(FDIM + k) * FDIM + o] = acc;
    // W2a transpose
    g_WcT[(size_t)k * FDIM + o] = W2[(size_t)o * K2 + k];

    // c2[o] = sum_j W1s[j]*W2b[o,j] ; c3[o] = b2[o] + D * sum_j b1[j]*W2b[o,j]
    float t1 = g_W1s[k] * w2b[k];
    float t2 = b1[k] * w2b[k];
    #pragma unroll
    for (int d = 32; d; d >>= 1) { t1 += __shfl_down(t1, d); t2 += __shfl_down(t2, d); }
    __shared__ float r1[4], r2[4];
    int wv = k >> 6, ln = k & 63;
    if (ln == 0) { r1[wv] = t1; r2[wv] = t2; }
    __syncthreads();
    if (k == 0) {
        float s1 = 0.f, s2 = 0.f;
        #pragma unroll
        for (int w = 0; w < 4; ++w) { s1 += r1[w]; s2 += r2[w]; }
        g_c2[o] = s1;
        g_c3[o] = b2[o] + Dmul * s2;
    }
}

// ---------- main: 32 nodes/block, gather + fused GEMM + normalize ----------
__global__ __launch_bounds__(256, 2) void gs_main(
    const float* __restrict__ feat_data,
    const float* __restrict__ feats,
    const int*   __restrict__ adj,
    const int*   __restrict__ in1, int B1,
    const int*   __restrict__ in2, int B2,
    float* __restrict__ out)
{
    __shared__ float Xs[TM][K2];      // 64 KB: [NF | A] per node
    __shared__ float Ws[KB * FDIM];   // 8 KB: staged Wc rows
    __shared__ float Sdeg[TM];

    int tid  = threadIdx.x;
    int wave = tid >> 6, lane = tid & 63;
    int base = blockIdx.x * TM;
    int total = B1 + B2;
    const float4* fd4 = (const float4*)feat_data;

    // ---- phase 1: gather. Each wave handles one node per g-iteration.
    for (int g = 0; g < TM / 4; ++g) {
        int m = g * 4 + wave;
        int t = base + m;
        if (t >= total) continue;
        int node = (t < B1) ? in1[t] : in2[t - B1];

        int idx = 0; float deg = 0.f;
        if (lane < DNB) {
            idx = adj[(size_t)node * DNB + lane];
            deg = feats[(size_t)idx * FDIM];    // row-constant degree
        }
        float dsum = deg;
        #pragma unroll
        for (int d = 16; d; d >>= 1) dsum += __shfl_down(dsum, d);
        if (lane == 0) Sdeg[m] = dsum;

        float4 nf = fd4[(size_t)node * 64 + lane];
        float4 a = make_float4(0.f, 0.f, 0.f, 0.f);
        #pragma unroll
        for (int d = 0; d < DNB; ++d) {
            int nb = __shfl(idx, d);
            float4 v = fd4[(size_t)nb * 64 + lane];
            a.x += v.x; a.y += v.y; a.z += v.z; a.w += v.w;
        }
        float4* xr = (float4*)(&Xs[m][0]);
        xr[lane]      = nf;
        xr[64 + lane] = a;
    }
    __syncthreads();

    // ---- phase 2: out_tile = X (32x512) @ WcT (512x256), 4x8 micro-tile
    int tn = tid & 31, tmg = tid >> 5;
    float acc[4][8];
    #pragma unroll
    for (int r = 0; r < 4; ++r)
        #pragma unroll
        for (int c = 0; c < 8; ++c) acc[r][c] = 0.f;

    const float4* Wc4 = (const float4*)g_WcT;
    float4* Ws4 = (float4*)Ws;

    for (int kb = 0; kb < K2 / KB; ++kb) {
        #pragma unroll
        for (int i = 0; i < KB * (FDIM / 4) / 256; ++i)   // 2 float4 per thread
            Ws4[i * 256 + tid] = Wc4[(size_t)kb * KB * (FDIM / 4) + i * 256 + tid];
        __syncthreads();
        #pragma unroll
        for (int k = 0; k < KB; ++k) {
            float xv[4];
            #pragma unroll
            for (int r = 0; r < 4; ++r) xv[r] = Xs[tmg * 4 + r][kb * KB + k];
            float4 w0 = Ws4[k * 64 + tn * 2];
            float4 w1 = Ws4[k * 64 + tn * 2 + 1];
            float wv[8] = {w0.x, w0.y, w0.z, w0.w, w1.x, w1.y, w1.z, w1.w};
            #pragma unroll
            for (int r = 0; r < 4; ++r)
                #pragma unroll
                for (int c = 0; c < 8; ++c)
                    acc[r][c] = fmaf(xv[r], wv[c], acc[r][c]);
        }
        __syncthreads();
    }

    // ---- epilogue: add degree/bias terms, L2-normalize rows, store
    int o0 = tn * 8;
    float4 c2a = *(const float4*)(g_c2 + o0), c2b = *(const float4*)(g_c2 + o0 + 4);
    float4 c3a = *(const float4*)(g_c3 + o0), c3b = *(const float4*)(g_c3 + o0 + 4);
    float c2v[8] = {c2a.x, c2a.y, c2a.z, c2a.w, c2b.x, c2b.y, c2b.z, c2b.w};
    float c3v[8] = {c3a.x, c3a.y, c3a.z, c3a.w, c3b.x, c3b.y, c3b.z, c3b.w};

    #pragma unroll
    for (int r = 0; r < 4; ++r) {
        int m = tmg * 4 + r;
        int t = base + m;
        if (t >= total) continue;
        float sd = Sdeg[m];
        float v[8]; float ss = 0.f;
        #pragma unroll
        for (int c = 0; c < 8; ++c) {
            v[c] = acc[r][c] + sd * c2v[c] + c3v[c];
            ss += v[c] * v[c];
        }
        #pragma unroll
        for (int s = 16; s; s >>= 1) ss += __shfl_xor(ss, s);
        float inv = 1.0f / fmaxf(sqrtf(ss), 1e-12f);
        float4 s0 = make_float4(v[0] * inv, v[1] * inv, v[2] * inv, v[3] * inv);
        float4 s1 = make_float4(v[4] * inv, v[5] * inv, v[6] * inv, v[7] * inv);
        float4* op = (float4*)(out + (size_t)t * FDIM + o0);
        op[0] = s0; op[1] = s1;
    }
}

// ---------- small kernel for the NEG rows (avoids a straggler block) ----------
__global__ __launch_bounds__(256) void gs_small(
    const float* __restrict__ feat_data,
    const float* __restrict__ feats,
    const int*   __restrict__ adj,
    const int*   __restrict__ neg,
    int tbase,
    float* __restrict__ out)
{
    __shared__ float Xl[K2];
    __shared__ int   nbs[DNB];
    __shared__ float sdeg_s;
    __shared__ float red[4];

    int tid = threadIdx.x;
    int r = blockIdx.x;
    int node = neg[r];
    if (tid < DNB) nbs[tid] = adj[(size_t)node * DNB + tid];
    __syncthreads();

    float a = 0.f;
    #pragma unroll 8
    for (int d = 0; d < DNB; ++d) a += feat_data[(size_t)nbs[d] * FDIM + tid];
    Xl[tid]        = feat_data[(size_t)node * FDIM + tid];
    Xl[FDIM + tid] = a;

    float deg = 0.f;
    if (tid < DNB) deg = feats[(size_t)nbs[tid] * FDIM];
    #pragma unroll
    for (int s = 16; s; s >>= 1) deg += __shfl_down(deg, s);
    if (tid == 0) sdeg_s = deg;
    __syncthreads();

    float acc = 0.f;
    int o = tid;
    #pragma unroll 8
    for (int k = 0; k < K2; ++k)
        acc = fmaf(Xl[k], g_WcT[(size_t)k * FDIM + o], acc);
    float val = acc + sdeg_s * g_c2[o] + g_c3[o];

    float ss = val * val;
    #pragma unroll
    for (int s = 32; s; s >>= 1) ss += __shfl_xor(ss, s);
    int wv = tid >> 6;
    if ((tid & 63) == 0) red[wv] = ss;
    __syncthreads();
    float tot = red[0] + red[1] + red[2] + red[3];
    float inv = 1.0f / fmaxf(sqrtf(tot), 1e-12f);
    out[(size_t)(tbase + r) * FDIM + o] = val * inv;
}

extern "C" void kernel_launch(void* const* d_in, const int* in_sizes, int n_in,
                              void* d_out, int out_size, void* d_ws, size_t ws_size,
                              hipStream_t stream) {
    const float* feat_data = (const float*)d_in[0];
    const float* feats     = (const float*)d_in[1];
    const float* W1        = (const float*)d_in[2];
    const float* b1        = (const float*)d_in[3];
    const float* W2        = (const float*)d_in[4];
    const float* b2        = (const float*)d_in[5];
    const int*   adj       = (const int*)d_in[6];
    const int*   in1       = (const int*)d_in[7];
    const int*   in2       = (const int*)d_in[8];
    const int*   neg       = (const int*)d_in[9];

    int B1 = in_sizes[7];
    int B2 = in_sizes[8];
    int Bn = in_sizes[9];
    int N  = in_sizes[0] / FDIM;
    int D  = in_sizes[6] / N;   // == 32

    float* out = (float*)d_out;

    pre_w1s<<<FDIM, 64, 0, stream>>>(W1);
    pre_wc<<<FDIM, 256, 0, stream>>>(W1, W2, b1, b2, (float)D);

    int totalMain = B1 + B2;
    int nblocks = (totalMain + TM - 1) / TM;
    gs_main<<<nblocks, 256, 0, stream>>>(feat_data, feats, adj, in1, B1, in2, B2, out);
    if (Bn > 0)
        gs_small<<<Bn, 256, 0, stream>>>(feat_data, feats, adj, neg, totalMain, out);
}